// Round 5
// baseline (89.049 us; speedup 1.0000x reference)
//
#include <hip/hip_runtime.h>

#define NT 8192
#define DM 4096
#define NE 8
#define NSLOT 16384
#define CAP 1024

// ---------------------------------------------------------------- logits GEMV
// Block = 512 threads = 8 waves; wave = 2 tokens. Gate (128 KB) staged into
// LDS in two 64 KB halves so VMEM carries only the x stream (134 MB, HBM
// floor ~21 us). 512 blocks -> 2 blocks/CU (LDS-limited), 4 waves/SIMD.
__global__ __launch_bounds__(512, 4) void k_logits(const float* __restrict__ x,
                                                   const float* __restrict__ gw,
                                                   float* __restrict__ logits) {
  __shared__ float4 gsh[4096];  // [e][512] float4 = 64 KB (one half of gate)
  const int tid = threadIdx.x;
  const int lane = tid & 63;
  const int wv = tid >> 6;                    // 0..7
  const int wave = blockIdx.x * 8 + wv;       // 0..4095
  const int t0 = wave * 2;
  const float4* __restrict__ xv = (const float4*)x;
  const float4* __restrict__ gv = (const float4*)gw;

  float acc[2][8];
#pragma unroll
  for (int t = 0; t < 2; ++t)
#pragma unroll
    for (int e = 0; e < 8; ++e) acc[t][e] = 0.f;

  for (int h = 0; h < 2; ++h) {
    if (h) __syncthreads();  // protect LDS before overwrite
    // stage half h: gate row e, float4 cols [h*512, h*512+512)
#pragma unroll
    for (int k = 0; k < 8; ++k) {
      const int f = tid + k * 512;            // 0..4095
      const int e = f >> 9, j = f & 511;
      gsh[f] = gv[e * 1024 + h * 512 + j];
    }
    __syncthreads();

    const size_t xb = (size_t)t0 * 1024 + h * 512;
#pragma unroll 2
    for (int c = 0; c < 8; ++c) {
      const int off = c * 64 + lane;
      const float4 x0 = xv[xb + off];
      const float4 x1 = xv[xb + 1024 + off];
#pragma unroll
      for (int e = 0; e < 8; ++e) {
        const float4 g = gsh[e * 512 + off];
        acc[0][e] = fmaf(x0.x, g.x, acc[0][e]);
        acc[0][e] = fmaf(x0.y, g.y, acc[0][e]);
        acc[0][e] = fmaf(x0.z, g.z, acc[0][e]);
        acc[0][e] = fmaf(x0.w, g.w, acc[0][e]);
        acc[1][e] = fmaf(x1.x, g.x, acc[1][e]);
        acc[1][e] = fmaf(x1.y, g.y, acc[1][e]);
        acc[1][e] = fmaf(x1.z, g.z, acc[1][e]);
        acc[1][e] = fmaf(x1.w, g.w, acc[1][e]);
      }
    }
  }

  float val = 0.f;
#pragma unroll
  for (int t = 0; t < 2; ++t)
#pragma unroll
    for (int e = 0; e < 8; ++e) {
      float v = acc[t][e];
#pragma unroll
      for (int s = 32; s > 0; s >>= 1) v += __shfl_xor(v, s, 64);
      if (lane == t * 8 + e) val = v;
    }
  if (lane < 16) logits[(size_t)wave * 16 + lane] = val;
}

// ---------------------------------------------------------------- routing
__global__ __launch_bounds__(256) void k_route(const float* __restrict__ logits,
                                               int* __restrict__ topk_idx,
                                               float* __restrict__ topk_p,
                                               unsigned char* __restrict__ flat_e,
                                               float* __restrict__ partials,
                                               int* __restrict__ usage) {
  const int n = blockIdx.x * blockDim.x + threadIdx.x;
  float l[8];
  const float4 a = ((const float4*)logits)[n * 2];
  const float4 b = ((const float4*)logits)[n * 2 + 1];
  l[0] = a.x; l[1] = a.y; l[2] = a.z; l[3] = a.w;
  l[4] = b.x; l[5] = b.y; l[6] = b.z; l[7] = b.w;

  float m = l[0];
#pragma unroll
  for (int e = 1; e < 8; ++e) m = fmaxf(m, l[e]);
  float ex[8];
  float s = 0.f;
#pragma unroll
  for (int e = 0; e < 8; ++e) { ex[e] = expf(l[e] - m); s += ex[e]; }
  const float lse = m + logf(s);

  // top-2 with earliest-index tie-break (strict >)
  float b0 = l[0]; int i0 = 0;
#pragma unroll
  for (int e = 1; e < 8; ++e) if (l[e] > b0) { b0 = l[e]; i0 = e; }
  float b1 = -3.4e38f; int i1 = 0;
#pragma unroll
  for (int e = 0; e < 8; ++e) if (e != i0 && l[e] > b1) { b1 = l[e]; i1 = e; }

  const float t1 = expf(b1 - b0);
  const float ss = 1.f + t1;
  float p0 = 1.f / ss, p1 = t1 / ss;
  float s2 = p0 + p1;
  s2 = fmaxf(s2, 1e-8f);
  p0 /= s2; p1 /= s2;

  topk_idx[2 * n] = i0; topk_idx[2 * n + 1] = i1;
  topk_p[2 * n] = p0;   topk_p[2 * n + 1] = p1;
  flat_e[2 * n] = (unsigned char)i0; flat_e[2 * n + 1] = (unsigned char)i1;

  // deterministic per-block partials: 8 expert prob-sums + sum(lse^2)
  const int lane = threadIdx.x & 63, wid = threadIdx.x >> 6;
  __shared__ float wred[4][9];
  float vals[9];
#pragma unroll
  for (int e = 0; e < 8; ++e) vals[e] = ex[e] / s;
  vals[8] = lse * lse;
#pragma unroll
  for (int r = 0; r < 9; ++r) {
    float v = vals[r];
#pragma unroll
    for (int sh = 32; sh > 0; sh >>= 1) v += __shfl_xor(v, sh, 64);
    if (lane == 0) wred[wid][r] = v;
  }
  __syncthreads();
  if (threadIdx.x < 9) {
    float acc2 = 0.f;
    for (int w = 0; w < 4; ++w) acc2 += wred[w][threadIdx.x];
    partials[blockIdx.x * 9 + threadIdx.x] = acc2;
  }
  if (blockIdx.x == 0 && threadIdx.x >= 32 && threadIdx.x < 40)
    usage[threadIdx.x - 32] = 0;
}

// ---------------------------------------------------------------- capacity select
// One block per expert. Stage+compact this expert's (u, idx) pairs into LDS,
// then 3x10-bit radix passes (descending on u) + one idx pass (ascending)
// entirely in LDS. Output threshold key (thr_u, thr_idx): keep(slot i, u) ==
// (u > thr_u) || (u == thr_u && i <= thr_idx) — bit-exact rank<CAP under
// (p desc, idx asc).
__global__ __launch_bounds__(256) void k_select(const float* __restrict__ flat_p,
                                                const unsigned char* __restrict__ flat_e,
                                                unsigned int* __restrict__ thr_u,
                                                int* __restrict__ thr_idx) {
  const int e = blockIdx.x;
  const int t = threadIdx.x;
  const int lane = t & 63, wid = t >> 6;
  __shared__ unsigned int u_lds[NSLOT];     // 64 KB
  __shared__ unsigned short i_lds[NSLOT];   // 32 KB
  __shared__ int hist[4][1024];             // 16 KB
  __shared__ int wtot[4];
  __shared__ int s_n, s_b, s_R2, s_cn;
  __shared__ int s_cand[16];

  const uint4* __restrict__ e4p = (const uint4*)flat_e;   // 16 bytes -> 16 items
  const float4* __restrict__ p4p = (const float4*)flat_p;

  // ---- phase 1: count my matches (items t+it*256 in uint4 granularity)
  int mycnt = 0;
#pragma unroll
  for (int it = 0; it < 4; ++it) {
    const uint4 ev = e4p[t + it * 256];
    const unsigned int w[4] = {ev.x, ev.y, ev.z, ev.w};
#pragma unroll
    for (int q = 0; q < 4; ++q)
#pragma unroll
      for (int b = 0; b < 4; ++b)
        mycnt += (((w[q] >> (8 * b)) & 0xffu) == (unsigned)e);
  }
  // exclusive prefix of mycnt across 256 threads (wave shfl + cross-wave)
  int pfx = mycnt;
#pragma unroll
  for (int off = 1; off < 64; off <<= 1) {
    const int tmp = __shfl_up(pfx, off, 64);
    if (lane >= off) pfx += tmp;
  }
  if (lane == 63) wtot[wid] = pfx;
  __syncthreads();
  int wbefore = 0;
  for (int w = 0; w < wid; ++w) wbefore += wtot[w];
  int pos = wbefore + pfx - mycnt;  // my exclusive offset
  if (t == 255) s_n = wbefore + pfx;
  __syncthreads();
  const int n = s_n;
  if (n <= CAP) {  // under capacity: keep everything for this expert
    if (t == 0) { thr_u[e] = 0u; thr_idx[e] = 0x7FFFFFFF; }
    return;
  }

  // ---- phase 2: re-read and write compacted (u, idx) at my offset
#pragma unroll
  for (int it = 0; it < 4; ++it) {
    const int vidx = t + it * 256;
    const uint4 ev = e4p[vidx];
    const unsigned int w[4] = {ev.x, ev.y, ev.z, ev.w};
    float4 pv[4];
#pragma unroll
    for (int q = 0; q < 4; ++q) pv[q] = p4p[vidx * 4 + q];
#pragma unroll
    for (int q = 0; q < 4; ++q) {
      const float pf[4] = {pv[q].x, pv[q].y, pv[q].z, pv[q].w};
#pragma unroll
      for (int b = 0; b < 4; ++b) {
        if (((w[q] >> (8 * b)) & 0xffu) == (unsigned)e) {
          u_lds[pos] = __float_as_uint(pf[b]);
          i_lds[pos] = (unsigned short)(vidx * 16 + q * 4 + b);
          ++pos;
        }
      }
    }
  }
  __syncthreads();

  // ---- radix passes on u (descending), 10 bits per pass, bits 29..0
  int R = CAP;
  unsigned int pref = 0;
  for (int pass = 0; pass < 3; ++pass) {
    const int shift = 20 - 10 * pass;
    for (int i = t; i < 4096; i += 256) ((int*)hist)[i] = 0;
    __syncthreads();
    for (int i = t; i < n; i += 256) {
      const unsigned int u = u_lds[i];
      if ((u >> (shift + 10)) == pref)
        atomicAdd(&hist[wid][(u >> shift) & 1023], 1);
    }
    __syncthreads();
    int c[4], chunk = 0;
#pragma unroll
    for (int k = 0; k < 4; ++k) {
      c[k] = hist[0][4 * t + k] + hist[1][4 * t + k] + hist[2][4 * t + k] +
             hist[3][4 * t + k];
      chunk += c[k];
    }
    // inclusive suffix scan of chunk across 256 threads
    int sfx = chunk;
#pragma unroll
    for (int off = 1; off < 64; off <<= 1) {
      const int tmp = __shfl_down(sfx, off, 64);
      if (lane + off < 64) sfx += tmp;
    }
    if (lane == 0) wtot[wid] = sfx;
    __syncthreads();
    int wafter = 0;
    for (int w = wid + 1; w < 4; ++w) wafter += wtot[w];
    const int after = sfx + wafter - chunk;  // items in buckets > 4t+3
    if (after < R && after + chunk >= R) {   // unique crossing thread
      int sx = after, bf = -1, rf = 0;
#pragma unroll
      for (int k = 3; k >= 0; --k) {
        if (bf < 0 && sx < R && sx + c[k] >= R) { bf = 4 * t + k; rf = R - sx; }
        sx += c[k];
      }
      s_b = bf; s_R2 = rf;
    }
    __syncthreads();
    pref = (pref << 10) | (unsigned int)s_b;
    R = s_R2;
    __syncthreads();
  }
  const unsigned int ustar = pref;

  // ---- pass 3: ascending rank on idx among items with u == ustar
  for (int i = t; i < 4096; i += 256) ((int*)hist)[i] = 0;
  if (t == 0) s_cn = 0;
  __syncthreads();
  for (int i = t; i < n; i += 256) {
    if (u_lds[i] == ustar) atomicAdd(&hist[wid][i_lds[i] >> 4], 1);
  }
  __syncthreads();
  int c[4], chunk = 0;
#pragma unroll
  for (int k = 0; k < 4; ++k) {
    c[k] = hist[0][4 * t + k] + hist[1][4 * t + k] + hist[2][4 * t + k] +
           hist[3][4 * t + k];
    chunk += c[k];
  }
  int pfa = chunk;
#pragma unroll
  for (int off = 1; off < 64; off <<= 1) {
    const int tmp = __shfl_up(pfa, off, 64);
    if (lane >= off) pfa += tmp;
  }
  if (lane == 63) wtot[wid] = pfa;
  __syncthreads();
  int wb = 0;
  for (int w = 0; w < wid; ++w) wb += wtot[w];
  const int before = wb + pfa - chunk;  // items in buckets < 4t
  if (before < R && before + chunk >= R) {
    int cum = before, bf = -1, rf = 0;
#pragma unroll
    for (int k = 0; k < 4; ++k) {
      if (bf < 0 && cum < R && cum + c[k] >= R) { bf = 4 * t + k; rf = R - cum; }
      cum += c[k];
    }
    s_b = bf; s_R2 = rf;
  }
  __syncthreads();
  const int b3 = s_b, R4 = s_R2;
  // collect the <=16 candidates in bucket b3 (idx in [b3*16, b3*16+16))
  for (int i = t; i < n; i += 256) {
    if (u_lds[i] == ustar && (i_lds[i] >> 4) == b3)
      s_cand[atomicAdd(&s_cn, 1)] = (int)i_lds[i];
  }
  __syncthreads();
  if (t == 0) {
    const int cn = s_cn;
    int ans = 0x7FFFFFFF;
    for (int a = 0; a < cn; ++a) {
      int r = 0;
      for (int b = 0; b < cn; ++b) r += (s_cand[b] < s_cand[a]);
      if (r == R4 - 1) ans = s_cand[a];
    }
    thr_u[e] = ustar;
    thr_idx[e] = ans;
  }
}

// ---------------------------------------------------------------- finalize
__global__ __launch_bounds__(256) void k_final(const int* __restrict__ topk_idx,
                                               const float* __restrict__ topk_p,
                                               const unsigned int* __restrict__ thr_u,
                                               const int* __restrict__ thr_idx,
                                               float* __restrict__ out,
                                               int* __restrict__ usage) {
  const int n = blockIdx.x * blockDim.x + threadIdx.x;
  const int i0 = topk_idx[2 * n], i1 = topk_idx[2 * n + 1];
  const float p0 = topk_p[2 * n], p1 = topk_p[2 * n + 1];
  const unsigned int u0 = __float_as_uint(p0), u1 = __float_as_uint(p1);
  const unsigned int tu0 = thr_u[i0], tu1 = thr_u[i1];
  const int ti0 = thr_idx[i0], ti1 = thr_idx[i1];
  const bool k0 = (u0 > tu0) || (u0 == tu0 && (2 * n) <= ti0);
  const bool k1 = (u1 > tu1) || (u1 == tu1 && (2 * n + 1) <= ti1);
  out[2 * n]     = k0 ? (float)i0 : -1.0f;
  out[2 * n + 1] = k1 ? (float)i1 : -1.0f;
  out[NSLOT + 2 * n]     = k0 ? p0 : 0.0f;
  out[NSLOT + 2 * n + 1] = k1 ? p1 : 0.0f;
  if (k0) atomicAdd(&usage[i0], 1);
}

__global__ __launch_bounds__(64) void k_loss(const float* __restrict__ partials,
                                             const int* __restrict__ usage,
                                             float* __restrict__ out) {
  __shared__ float ps[9];
  const int t = threadIdx.x;
  if (t < 9) {
    float a = 0.f;
    for (int b = 0; b < 32; ++b) a += partials[b * 9 + t];
    ps[t] = a;
  }
  __syncthreads();
  if (t == 0) {
    float lb = 0.f;
    for (int e = 0; e < 8; ++e) lb += ps[e] * (float)usage[e];
    out[2 * NSLOT]     = lb * (0.01f / (float)(NT * NE));
    out[2 * NSLOT + 1] = (ps[8] / (float)NT) * 0.001f;
  }
  if (t < 8) out[2 * NSLOT + 2 + t] = (float)usage[t];
}

extern "C" void kernel_launch(void* const* d_in, const int* in_sizes, int n_in,
                              void* d_out, int out_size, void* d_ws, size_t ws_size,
                              hipStream_t stream) {
  const float* x  = (const float*)d_in[0];
  const float* gw = (const float*)d_in[1];
  float* out = (float*)d_out;
  char* ws = (char*)d_ws;

  float* logits         = (float*)(ws);                    // 262144 B
  int* topk_idx         = (int*)(ws + 262144);             // 65536 B
  float* topk_p         = (float*)(ws + 327680);           // 65536 B
  unsigned char* flat_e = (unsigned char*)(ws + 393216);   // 16384 B
  unsigned int* thr_u   = (unsigned int*)(ws + 409600);    // 32 B
  int* thr_idx          = (int*)(ws + 409728);             // 32 B
  float* partials       = (float*)(ws + 475136);           // 1152 B
  int* usage            = (int*)(ws + 476288);             // 32 B

  hipLaunchKernelGGL(k_logits, dim3(512), dim3(512), 0, stream, x, gw, logits);
  hipLaunchKernelGGL(k_route, dim3(32), dim3(256), 0, stream, logits, topk_idx,
                     topk_p, flat_e, partials, usage);
  hipLaunchKernelGGL(k_select, dim3(8), dim3(256), 0, stream, topk_p, flat_e,
                     thr_u, thr_idx);
  hipLaunchKernelGGL(k_final, dim3(32), dim3(256), 0, stream, topk_idx, topk_p,
                     thr_u, thr_idx, out, usage);
  hipLaunchKernelGGL(k_loss, dim3(1), dim3(64), 0, stream, partials, usage, out);
}

// Round 6
// 85.108 us; speedup vs baseline: 1.0463x; 1.0463x over previous
//
#include <hip/hip_runtime.h>

#define NT 8192
#define DM 4096
#define NE 8
#define NSLOT 16384
#define CAP 1024
#define NPAIR 4096   // token pairs
#define QF 256       // float4 per quarter-row (1024 dims)

// ---------------------------------------------------------------- logits GEMV
// Wave = 2 tokens x 1 quarter-row (1024 dims). All 8 x-float4 loads issued
// up-front (8 KB/wave in flight, no dependent consumer between them) ->
// latency-hiding by ILP, not just TLP. Gate quarter (32 KB) staged in LDS
// once per block. 4096 blocks x 4 waves = 16384 waves, 16 waves/CU.
// Output: per-quarter partial logits lpart[q][pair][16] (t*8+e), summed
// deterministically in k_route.
__global__ __launch_bounds__(256, 4) void k_logits(const float* __restrict__ x,
                                                   const float* __restrict__ gw,
                                                   float* __restrict__ lpart) {
  __shared__ float4 gsh[8][QF];  // 32 KB: gate quarter, all 8 experts
  const int tid = threadIdx.x;
  const int lane = tid & 63;
  const int wv = tid >> 6;                    // 0..3
  const int b = blockIdx.x;                   // 0..4095
  const int q = b & 3;                        // quarter
  const int pair = (b >> 2) * 4 + wv;         // 0..4095
  const int t0 = pair * 2;
  const float4* __restrict__ xv = (const float4*)x;
  const float4* __restrict__ gv = (const float4*)gw;

  // issue all 8 independent x loads first
  float4 xr[2][4];
  const size_t xb0 = (size_t)t0 * 1024 + q * QF;
#pragma unroll
  for (int k = 0; k < 4; ++k) xr[0][k] = xv[xb0 + k * 64 + lane];
#pragma unroll
  for (int k = 0; k < 4; ++k) xr[1][k] = xv[xb0 + 1024 + k * 64 + lane];

  // stage gate quarter: 2048 float4 / 256 threads = 8 each (L2-hot)
#pragma unroll
  for (int k = 0; k < 8; ++k) {
    const int f = tid + k * 256;              // 0..2047
    const int e = f >> 8, j = f & 255;
    gsh[e][j] = gv[e * 1024 + q * QF + j];
  }
  __syncthreads();

  float acc[2][8];
#pragma unroll
  for (int t = 0; t < 2; ++t)
#pragma unroll
    for (int e = 0; e < 8; ++e) acc[t][e] = 0.f;

#pragma unroll
  for (int k = 0; k < 4; ++k) {
    const int off = k * 64 + lane;
#pragma unroll
    for (int e = 0; e < 8; ++e) {
      const float4 g = gsh[e][off];
      acc[0][e] = fmaf(xr[0][k].x, g.x, acc[0][e]);
      acc[0][e] = fmaf(xr[0][k].y, g.y, acc[0][e]);
      acc[0][e] = fmaf(xr[0][k].z, g.z, acc[0][e]);
      acc[0][e] = fmaf(xr[0][k].w, g.w, acc[0][e]);
      acc[1][e] = fmaf(xr[1][k].x, g.x, acc[1][e]);
      acc[1][e] = fmaf(xr[1][k].y, g.y, acc[1][e]);
      acc[1][e] = fmaf(xr[1][k].z, g.z, acc[1][e]);
      acc[1][e] = fmaf(xr[1][k].w, g.w, acc[1][e]);
    }
  }

  float val = 0.f;
#pragma unroll
  for (int t = 0; t < 2; ++t)
#pragma unroll
    for (int e = 0; e < 8; ++e) {
      float v = acc[t][e];
#pragma unroll
      for (int s = 32; s > 0; s >>= 1) v += __shfl_xor(v, s, 64);
      if (lane == t * 8 + e) val = v;
    }
  if (lane < 16) lpart[((size_t)q * NPAIR + pair) * 16 + lane] = val;
}

// ---------------------------------------------------------------- routing
__global__ __launch_bounds__(256) void k_route(const float* __restrict__ lpart,
                                               int* __restrict__ topk_idx,
                                               float* __restrict__ topk_p,
                                               unsigned char* __restrict__ flat_e,
                                               float* __restrict__ partials,
                                               int* __restrict__ usage) {
  const int n = blockIdx.x * blockDim.x + threadIdx.x;
  const float4* __restrict__ lp4 = (const float4*)lpart;
  float l[8] = {0.f, 0.f, 0.f, 0.f, 0.f, 0.f, 0.f, 0.f};
#pragma unroll
  for (int q = 0; q < 4; ++q) {
    const size_t base = ((size_t)q * NPAIR + (n >> 1)) * 4 + (size_t)(n & 1) * 2;
    const float4 a = lp4[base];
    const float4 b = lp4[base + 1];
    l[0] += a.x; l[1] += a.y; l[2] += a.z; l[3] += a.w;
    l[4] += b.x; l[5] += b.y; l[6] += b.z; l[7] += b.w;
  }

  float m = l[0];
#pragma unroll
  for (int e = 1; e < 8; ++e) m = fmaxf(m, l[e]);
  float ex[8];
  float s = 0.f;
#pragma unroll
  for (int e = 0; e < 8; ++e) { ex[e] = expf(l[e] - m); s += ex[e]; }
  const float lse = m + logf(s);

  // top-2 with earliest-index tie-break (strict >)
  float b0 = l[0]; int i0 = 0;
#pragma unroll
  for (int e = 1; e < 8; ++e) if (l[e] > b0) { b0 = l[e]; i0 = e; }
  float b1 = -3.4e38f; int i1 = 0;
#pragma unroll
  for (int e = 0; e < 8; ++e) if (e != i0 && l[e] > b1) { b1 = l[e]; i1 = e; }

  const float t1 = expf(b1 - b0);
  const float ss = 1.f + t1;
  float p0 = 1.f / ss, p1 = t1 / ss;
  float s2 = p0 + p1;
  s2 = fmaxf(s2, 1e-8f);
  p0 /= s2; p1 /= s2;

  topk_idx[2 * n] = i0; topk_idx[2 * n + 1] = i1;
  topk_p[2 * n] = p0;   topk_p[2 * n + 1] = p1;
  flat_e[2 * n] = (unsigned char)i0; flat_e[2 * n + 1] = (unsigned char)i1;

  // deterministic per-block partials: 8 expert prob-sums + sum(lse^2)
  const int lane = threadIdx.x & 63, wid = threadIdx.x >> 6;
  __shared__ float wred[4][9];
  float vals[9];
#pragma unroll
  for (int e = 0; e < 8; ++e) vals[e] = ex[e] / s;
  vals[8] = lse * lse;
#pragma unroll
  for (int r = 0; r < 9; ++r) {
    float v = vals[r];
#pragma unroll
    for (int sh = 32; sh > 0; sh >>= 1) v += __shfl_xor(v, sh, 64);
    if (lane == 0) wred[wid][r] = v;
  }
  __syncthreads();
  if (threadIdx.x < 9) {
    float acc2 = 0.f;
    for (int w = 0; w < 4; ++w) acc2 += wred[w][threadIdx.x];
    partials[blockIdx.x * 9 + threadIdx.x] = acc2;
  }
  if (blockIdx.x == 0 && threadIdx.x >= 32 && threadIdx.x < 40)
    usage[threadIdx.x - 32] = 0;
}

// ---------------------------------------------------------------- capacity select
// One block per expert. Stage+compact this expert's (u, idx) pairs into LDS,
// then 3x10-bit radix passes (descending on u) + one idx pass (ascending)
// entirely in LDS. Output threshold key (thr_u, thr_idx): keep(slot i, u) ==
// (u > thr_u) || (u == thr_u && i <= thr_idx) — bit-exact rank<CAP under
// (p desc, idx asc).
__global__ __launch_bounds__(256) void k_select(const float* __restrict__ flat_p,
                                                const unsigned char* __restrict__ flat_e,
                                                unsigned int* __restrict__ thr_u,
                                                int* __restrict__ thr_idx) {
  const int e = blockIdx.x;
  const int t = threadIdx.x;
  const int lane = t & 63, wid = t >> 6;
  __shared__ unsigned int u_lds[NSLOT];     // 64 KB
  __shared__ unsigned short i_lds[NSLOT];   // 32 KB
  __shared__ int hist[4][1024];             // 16 KB
  __shared__ int wtot[4];
  __shared__ int s_n, s_b, s_R2, s_cn;
  __shared__ int s_cand[16];

  const uint4* __restrict__ e4p = (const uint4*)flat_e;   // 16 bytes -> 16 items
  const float4* __restrict__ p4p = (const float4*)flat_p;

  // ---- phase 1: count my matches (items t+it*256 in uint4 granularity)
  int mycnt = 0;
#pragma unroll
  for (int it = 0; it < 4; ++it) {
    const uint4 ev = e4p[t + it * 256];
    const unsigned int w[4] = {ev.x, ev.y, ev.z, ev.w};
#pragma unroll
    for (int q = 0; q < 4; ++q)
#pragma unroll
      for (int b = 0; b < 4; ++b)
        mycnt += (((w[q] >> (8 * b)) & 0xffu) == (unsigned)e);
  }
  // exclusive prefix of mycnt across 256 threads (wave shfl + cross-wave)
  int pfx = mycnt;
#pragma unroll
  for (int off = 1; off < 64; off <<= 1) {
    const int tmp = __shfl_up(pfx, off, 64);
    if (lane >= off) pfx += tmp;
  }
  if (lane == 63) wtot[wid] = pfx;
  __syncthreads();
  int wbefore = 0;
  for (int w = 0; w < wid; ++w) wbefore += wtot[w];
  int pos = wbefore + pfx - mycnt;  // my exclusive offset
  if (t == 255) s_n = wbefore + pfx;
  __syncthreads();
  const int n = s_n;
  if (n <= CAP) {  // under capacity: keep everything for this expert
    if (t == 0) { thr_u[e] = 0u; thr_idx[e] = 0x7FFFFFFF; }
    return;
  }

  // ---- phase 2: re-read and write compacted (u, idx) at my offset
#pragma unroll
  for (int it = 0; it < 4; ++it) {
    const int vidx = t + it * 256;
    const uint4 ev = e4p[vidx];
    const unsigned int w[4] = {ev.x, ev.y, ev.z, ev.w};
    float4 pv[4];
#pragma unroll
    for (int q = 0; q < 4; ++q) pv[q] = p4p[vidx * 4 + q];
#pragma unroll
    for (int q = 0; q < 4; ++q) {
      const float pf[4] = {pv[q].x, pv[q].y, pv[q].z, pv[q].w};
#pragma unroll
      for (int b = 0; b < 4; ++b) {
        if (((w[q] >> (8 * b)) & 0xffu) == (unsigned)e) {
          u_lds[pos] = __float_as_uint(pf[b]);
          i_lds[pos] = (unsigned short)(vidx * 16 + q * 4 + b);
          ++pos;
        }
      }
    }
  }
  __syncthreads();

  // ---- radix passes on u (descending), 10 bits per pass, bits 29..0
  int R = CAP;
  unsigned int pref = 0;
  for (int pass = 0; pass < 3; ++pass) {
    const int shift = 20 - 10 * pass;
    for (int i = t; i < 4096; i += 256) ((int*)hist)[i] = 0;
    __syncthreads();
    for (int i = t; i < n; i += 256) {
      const unsigned int u = u_lds[i];
      if ((u >> (shift + 10)) == pref)
        atomicAdd(&hist[wid][(u >> shift) & 1023], 1);
    }
    __syncthreads();
    int c[4], chunk = 0;
#pragma unroll
    for (int k = 0; k < 4; ++k) {
      c[k] = hist[0][4 * t + k] + hist[1][4 * t + k] + hist[2][4 * t + k] +
             hist[3][4 * t + k];
      chunk += c[k];
    }
    // inclusive suffix scan of chunk across 256 threads
    int sfx = chunk;
#pragma unroll
    for (int off = 1; off < 64; off <<= 1) {
      const int tmp = __shfl_down(sfx, off, 64);
      if (lane + off < 64) sfx += tmp;
    }
    if (lane == 0) wtot[wid] = sfx;
    __syncthreads();
    int wafter = 0;
    for (int w = wid + 1; w < 4; ++w) wafter += wtot[w];
    const int after = sfx + wafter - chunk;  // items in buckets > 4t+3
    if (after < R && after + chunk >= R) {   // unique crossing thread
      int sx = after, bf = -1, rf = 0;
#pragma unroll
      for (int k = 3; k >= 0; --k) {
        if (bf < 0 && sx < R && sx + c[k] >= R) { bf = 4 * t + k; rf = R - sx; }
        sx += c[k];
      }
      s_b = bf; s_R2 = rf;
    }
    __syncthreads();
    pref = (pref << 10) | (unsigned int)s_b;
    R = s_R2;
    __syncthreads();
  }
  const unsigned int ustar = pref;

  // ---- pass 3: ascending rank on idx among items with u == ustar
  for (int i = t; i < 4096; i += 256) ((int*)hist)[i] = 0;
  if (t == 0) s_cn = 0;
  __syncthreads();
  for (int i = t; i < n; i += 256) {
    if (u_lds[i] == ustar) atomicAdd(&hist[wid][i_lds[i] >> 4], 1);
  }
  __syncthreads();
  int c[4], chunk = 0;
#pragma unroll
  for (int k = 0; k < 4; ++k) {
    c[k] = hist[0][4 * t + k] + hist[1][4 * t + k] + hist[2][4 * t + k] +
           hist[3][4 * t + k];
    chunk += c[k];
  }
  int pfa = chunk;
#pragma unroll
  for (int off = 1; off < 64; off <<= 1) {
    const int tmp = __shfl_up(pfa, off, 64);
    if (lane >= off) pfa += tmp;
  }
  if (lane == 63) wtot[wid] = pfa;
  __syncthreads();
  int wb = 0;
  for (int w = 0; w < wid; ++w) wb += wtot[w];
  const int before = wb + pfa - chunk;  // items in buckets < 4t
  if (before < R && before + chunk >= R) {
    int cum = before, bf = -1, rf = 0;
#pragma unroll
    for (int k = 0; k < 4; ++k) {
      if (bf < 0 && cum < R && cum + c[k] >= R) { bf = 4 * t + k; rf = R - cum; }
      cum += c[k];
    }
    s_b = bf; s_R2 = rf;
  }
  __syncthreads();
  const int b3 = s_b, R4 = s_R2;
  // collect the <=16 candidates in bucket b3 (idx in [b3*16, b3*16+16))
  for (int i = t; i < n; i += 256) {
    if (u_lds[i] == ustar && (i_lds[i] >> 4) == b3)
      s_cand[atomicAdd(&s_cn, 1)] = (int)i_lds[i];
  }
  __syncthreads();
  if (t == 0) {
    const int cn = s_cn;
    int ans = 0x7FFFFFFF;
    for (int a = 0; a < cn; ++a) {
      int r = 0;
      for (int b = 0; b < cn; ++b) r += (s_cand[b] < s_cand[a]);
      if (r == R4 - 1) ans = s_cand[a];
    }
    thr_u[e] = ustar;
    thr_idx[e] = ans;
  }
}

// ---------------------------------------------------------------- finalize
__global__ __launch_bounds__(256) void k_final(const int* __restrict__ topk_idx,
                                               const float* __restrict__ topk_p,
                                               const unsigned int* __restrict__ thr_u,
                                               const int* __restrict__ thr_idx,
                                               float* __restrict__ out,
                                               int* __restrict__ usage) {
  const int n = blockIdx.x * blockDim.x + threadIdx.x;
  const int i0 = topk_idx[2 * n], i1 = topk_idx[2 * n + 1];
  const float p0 = topk_p[2 * n], p1 = topk_p[2 * n + 1];
  const unsigned int u0 = __float_as_uint(p0), u1 = __float_as_uint(p1);
  const unsigned int tu0 = thr_u[i0], tu1 = thr_u[i1];
  const int ti0 = thr_idx[i0], ti1 = thr_idx[i1];
  const bool k0 = (u0 > tu0) || (u0 == tu0 && (2 * n) <= ti0);
  const bool k1 = (u1 > tu1) || (u1 == tu1 && (2 * n + 1) <= ti1);
  out[2 * n]     = k0 ? (float)i0 : -1.0f;
  out[2 * n + 1] = k1 ? (float)i1 : -1.0f;
  out[NSLOT + 2 * n]     = k0 ? p0 : 0.0f;
  out[NSLOT + 2 * n + 1] = k1 ? p1 : 0.0f;
  if (k0) atomicAdd(&usage[i0], 1);
}

__global__ __launch_bounds__(64) void k_loss(const float* __restrict__ partials,
                                             const int* __restrict__ usage,
                                             float* __restrict__ out) {
  __shared__ float ps[9];
  const int t = threadIdx.x;
  if (t < 9) {
    float a = 0.f;
    for (int b = 0; b < 32; ++b) a += partials[b * 9 + t];
    ps[t] = a;
  }
  __syncthreads();
  if (t == 0) {
    float lb = 0.f;
    for (int e = 0; e < 8; ++e) lb += ps[e] * (float)usage[e];
    out[2 * NSLOT]     = lb * (0.01f / (float)(NT * NE));
    out[2 * NSLOT + 1] = (ps[8] / (float)NT) * 0.001f;
  }
  if (t < 8) out[2 * NSLOT + 2 + t] = (float)usage[t];
}

extern "C" void kernel_launch(void* const* d_in, const int* in_sizes, int n_in,
                              void* d_out, int out_size, void* d_ws, size_t ws_size,
                              hipStream_t stream) {
  const float* x  = (const float*)d_in[0];
  const float* gw = (const float*)d_in[1];
  float* out = (float*)d_out;
  char* ws = (char*)d_ws;

  float* lpart          = (float*)(ws);                    // 1048576 B (4*4096*16*4)
  int* topk_idx         = (int*)(ws + 1048576);            // 65536 B
  float* topk_p         = (float*)(ws + 1114112);          // 65536 B
  unsigned char* flat_e = (unsigned char*)(ws + 1179648);  // 16384 B
  unsigned int* thr_u   = (unsigned int*)(ws + 1196032);   // 32 B
  int* thr_idx          = (int*)(ws + 1196160);            // 32 B
  float* partials       = (float*)(ws + 1196288);          // 1152 B
  int* usage            = (int*)(ws + 1197568);            // 32 B

  hipLaunchKernelGGL(k_logits, dim3(4096), dim3(256), 0, stream, x, gw, lpart);
  hipLaunchKernelGGL(k_route, dim3(32), dim3(256), 0, stream, lpart, topk_idx,
                     topk_p, flat_e, partials, usage);
  hipLaunchKernelGGL(k_select, dim3(8), dim3(256), 0, stream, topk_p, flat_e,
                     thr_u, thr_idx);
  hipLaunchKernelGGL(k_final, dim3(32), dim3(256), 0, stream, topk_idx, topk_p,
                     thr_u, thr_idx, out, usage);
  hipLaunchKernelGGL(k_loss, dim3(1), dim3(64), 0, stream, partials, usage, out);
}

// Round 7
// 55.499 us; speedup vs baseline: 1.6045x; 1.5335x over previous
//
#include <hip/hip_runtime.h>

#define NT 8192
#define DM 4096
#define NE 8
#define NSLOT 16384
#define CAP 1024

// ------------------------------------------------- fused logits + routing
// 1024 blocks x 256 threads; wave = 2 tokens x full 4096-dim row.
// After the cross-lane reduce, lanes 0/1 compute softmax/top-2/losses for
// their token inline. Outputs: topk_p, flat_e, per-block partials[9].
__global__ __launch_bounds__(256, 4) void k_logits_route(
    const float* __restrict__ x, const float* __restrict__ gw,
    float* __restrict__ topk_p, unsigned char* __restrict__ flat_e,
    float* __restrict__ partials) {
  const int tid = threadIdx.x;
  const int lane = tid & 63;
  const int wv = tid >> 6;                 // 0..3
  const int wave = blockIdx.x * 4 + wv;    // 0..4095
  const int t0 = wave * 2;
  const float4* __restrict__ xv = (const float4*)x;
  const float4* __restrict__ gv = (const float4*)gw;

  float acc[2][8];
#pragma unroll
  for (int t = 0; t < 2; ++t)
#pragma unroll
    for (int e = 0; e < 8; ++e) acc[t][e] = 0.f;

#pragma unroll 2
  for (int c = 0; c < 16; ++c) {
    const int off = c * 64 + lane;
    float4 g4[8];
#pragma unroll
    for (int e = 0; e < 8; ++e) g4[e] = gv[e * 1024 + off];
    const float4 x0 = xv[(size_t)t0 * 1024 + off];
    const float4 x1 = xv[(size_t)t0 * 1024 + 1024 + off];
#pragma unroll
    for (int e = 0; e < 8; ++e) {
      acc[0][e] = fmaf(x0.x, g4[e].x, acc[0][e]);
      acc[0][e] = fmaf(x0.y, g4[e].y, acc[0][e]);
      acc[0][e] = fmaf(x0.z, g4[e].z, acc[0][e]);
      acc[0][e] = fmaf(x0.w, g4[e].w, acc[0][e]);
      acc[1][e] = fmaf(x1.x, g4[e].x, acc[1][e]);
      acc[1][e] = fmaf(x1.y, g4[e].y, acc[1][e]);
      acc[1][e] = fmaf(x1.z, g4[e].z, acc[1][e]);
      acc[1][e] = fmaf(x1.w, g4[e].w, acc[1][e]);
    }
  }

  // cross-lane reduce: lane t*8+e ends up holding logit[t][e]
  float val = 0.f;
#pragma unroll
  for (int t = 0; t < 2; ++t)
#pragma unroll
    for (int e = 0; e < 8; ++e) {
      float v = acc[t][e];
#pragma unroll
      for (int s = 32; s > 0; s >>= 1) v += __shfl_xor(v, s, 64);
      if (lane == t * 8 + e) val = v;
    }

  // gather the 8 logits of token (lane&1) into every lane
  float l[8];
#pragma unroll
  for (int e = 0; e < 8; ++e) l[e] = __shfl(val, (lane & 1) * 8 + e, 64);

  // routing math (meaningful on lanes 0/1; harmless elsewhere)
  float m = l[0];
#pragma unroll
  for (int e = 1; e < 8; ++e) m = fmaxf(m, l[e]);
  float ex[8];
  float s = 0.f;
#pragma unroll
  for (int e = 0; e < 8; ++e) { ex[e] = expf(l[e] - m); s += ex[e]; }
  const float lse = m + logf(s);

  float b0 = l[0]; int i0 = 0;
#pragma unroll
  for (int e = 1; e < 8; ++e) if (l[e] > b0) { b0 = l[e]; i0 = e; }
  float b1 = -3.4e38f; int i1 = 0;
#pragma unroll
  for (int e = 0; e < 8; ++e) if (e != i0 && l[e] > b1) { b1 = l[e]; i1 = e; }

  const float t1 = expf(b1 - b0);
  const float ss = 1.f + t1;
  float p0 = 1.f / ss, p1 = t1 / ss;
  float s2 = p0 + p1;
  s2 = fmaxf(s2, 1e-8f);
  p0 /= s2; p1 /= s2;

  __shared__ float pr[8][9];
  if (lane < 2) {
    const int tok = t0 + lane;
    topk_p[2 * tok] = p0; topk_p[2 * tok + 1] = p1;
    flat_e[2 * tok] = (unsigned char)i0; flat_e[2 * tok + 1] = (unsigned char)i1;
#pragma unroll
    for (int e = 0; e < 8; ++e) pr[wv * 2 + lane][e] = ex[e] / s;
    pr[wv * 2 + lane][8] = lse * lse;
  }
  __syncthreads();
  if (tid < 9) {
    float a = 0.f;
#pragma unroll
    for (int r = 0; r < 8; ++r) a += pr[r][tid];
    partials[blockIdx.x * 9 + tid] = a;
  }
}

// ------------------------------------------------- fused select + finalize
// One block per expert. Compact this expert's (u, idx) pairs into LDS
// (always), then if over capacity run 3x10-bit radix (descending on u) +
// one ascending idx pass to get the exact threshold key. Finally write the
// outputs for exactly this expert's slots (disjoint coverage, no atomics)
// and usage[e] = # kept even slots.
__global__ __launch_bounds__(256) void k_select_final(
    const float* __restrict__ flat_p, const unsigned char* __restrict__ flat_e,
    float* __restrict__ out, int* __restrict__ usage) {
  const int e = blockIdx.x;
  const int t = threadIdx.x;
  const int lane = t & 63, wid = t >> 6;
  __shared__ unsigned int u_lds[NSLOT];     // 64 KB
  __shared__ unsigned short i_lds[NSLOT];   // 32 KB
  __shared__ int hist[4][1024];             // 16 KB
  __shared__ int wtot[4];
  __shared__ int s_n, s_b, s_R2, s_cn, s_ti;
  __shared__ int s_cand[16];

  const uint4* __restrict__ e4p = (const uint4*)flat_e;
  const float4* __restrict__ p4p = (const float4*)flat_p;

  // ---- phase 1: count my matches
  int mycnt = 0;
#pragma unroll
  for (int it = 0; it < 4; ++it) {
    const uint4 ev = e4p[t + it * 256];
    const unsigned int w[4] = {ev.x, ev.y, ev.z, ev.w};
#pragma unroll
    for (int q = 0; q < 4; ++q)
#pragma unroll
      for (int b = 0; b < 4; ++b)
        mycnt += (((w[q] >> (8 * b)) & 0xffu) == (unsigned)e);
  }
  int pfx = mycnt;
#pragma unroll
  for (int off = 1; off < 64; off <<= 1) {
    const int tmp = __shfl_up(pfx, off, 64);
    if (lane >= off) pfx += tmp;
  }
  if (lane == 63) wtot[wid] = pfx;
  __syncthreads();
  int wbefore = 0;
  for (int w = 0; w < wid; ++w) wbefore += wtot[w];
  int pos = wbefore + pfx - mycnt;
  if (t == 255) s_n = wbefore + pfx;
  __syncthreads();
  const int n = s_n;

  // ---- phase 2: compact (always)
#pragma unroll
  for (int it = 0; it < 4; ++it) {
    const int vidx = t + it * 256;
    const uint4 ev = e4p[vidx];
    const unsigned int w[4] = {ev.x, ev.y, ev.z, ev.w};
    float4 pv[4];
#pragma unroll
    for (int q = 0; q < 4; ++q) pv[q] = p4p[vidx * 4 + q];
#pragma unroll
    for (int q = 0; q < 4; ++q) {
      const float pf[4] = {pv[q].x, pv[q].y, pv[q].z, pv[q].w};
#pragma unroll
      for (int b = 0; b < 4; ++b) {
        if (((w[q] >> (8 * b)) & 0xffu) == (unsigned)e) {
          u_lds[pos] = __float_as_uint(pf[b]);
          i_lds[pos] = (unsigned short)(vidx * 16 + q * 4 + b);
          ++pos;
        }
      }
    }
  }
  __syncthreads();

  unsigned int tu = 0u;
  int ti_ = 0x7FFFFFFF;
  if (n > CAP) {
    // ---- radix on u (descending), 10 bits/pass, bits 29..0
    int R = CAP;
    unsigned int pref = 0;
    for (int pass = 0; pass < 3; ++pass) {
      const int shift = 20 - 10 * pass;
      for (int i = t; i < 4096; i += 256) ((int*)hist)[i] = 0;
      __syncthreads();
      for (int i = t; i < n; i += 256) {
        const unsigned int u = u_lds[i];
        if ((u >> (shift + 10)) == pref)
          atomicAdd(&hist[wid][(u >> shift) & 1023], 1);
      }
      __syncthreads();
      int c[4], chunk = 0;
#pragma unroll
      for (int k = 0; k < 4; ++k) {
        c[k] = hist[0][4 * t + k] + hist[1][4 * t + k] + hist[2][4 * t + k] +
               hist[3][4 * t + k];
        chunk += c[k];
      }
      int sfx = chunk;
#pragma unroll
      for (int off = 1; off < 64; off <<= 1) {
        const int tmp = __shfl_down(sfx, off, 64);
        if (lane + off < 64) sfx += tmp;
      }
      if (lane == 0) wtot[wid] = sfx;
      __syncthreads();
      int wafter = 0;
      for (int w = wid + 1; w < 4; ++w) wafter += wtot[w];
      const int after = sfx + wafter - chunk;
      if (after < R && after + chunk >= R) {
        int sx = after, bf = -1, rf = 0;
#pragma unroll
        for (int k = 3; k >= 0; --k) {
          if (bf < 0 && sx < R && sx + c[k] >= R) { bf = 4 * t + k; rf = R - sx; }
          sx += c[k];
        }
        s_b = bf; s_R2 = rf;
      }
      __syncthreads();
      pref = (pref << 10) | (unsigned int)s_b;
      R = s_R2;
      __syncthreads();
    }
    const unsigned int ustar = pref;

    // ---- ascending idx pass among u == ustar
    for (int i = t; i < 4096; i += 256) ((int*)hist)[i] = 0;
    if (t == 0) s_cn = 0;
    __syncthreads();
    for (int i = t; i < n; i += 256) {
      if (u_lds[i] == ustar) atomicAdd(&hist[wid][i_lds[i] >> 4], 1);
    }
    __syncthreads();
    int c[4], chunk = 0;
#pragma unroll
    for (int k = 0; k < 4; ++k) {
      c[k] = hist[0][4 * t + k] + hist[1][4 * t + k] + hist[2][4 * t + k] +
             hist[3][4 * t + k];
      chunk += c[k];
    }
    int pfa = chunk;
#pragma unroll
    for (int off = 1; off < 64; off <<= 1) {
      const int tmp = __shfl_up(pfa, off, 64);
      if (lane >= off) pfa += tmp;
    }
    if (lane == 63) wtot[wid] = pfa;
    __syncthreads();
    int wb = 0;
    for (int w = 0; w < wid; ++w) wb += wtot[w];
    const int before = wb + pfa - chunk;
    if (before < R && before + chunk >= R) {
      int cum = before, bf = -1, rf = 0;
#pragma unroll
      for (int k = 0; k < 4; ++k) {
        if (bf < 0 && cum < R && cum + c[k] >= R) { bf = 4 * t + k; rf = R - cum; }
        cum += c[k];
      }
      s_b = bf; s_R2 = rf;
    }
    __syncthreads();
    const int b3 = s_b, R4 = s_R2;
    for (int i = t; i < n; i += 256) {
      if (u_lds[i] == ustar && (i_lds[i] >> 4) == b3)
        s_cand[atomicAdd(&s_cn, 1)] = (int)i_lds[i];
    }
    __syncthreads();
    if (t == 0) {
      const int cn = s_cn;
      int ans = 0x7FFFFFFF;
      for (int a = 0; a < cn; ++a) {
        int r = 0;
        for (int b = 0; b < cn; ++b) r += (s_cand[b] < s_cand[a]);
        if (r == R4 - 1) ans = s_cand[a];
      }
      s_ti = ans;
    }
    __syncthreads();
    tu = ustar;
    ti_ = s_ti;
  }

  // ---- output phase: exactly this expert's slots (disjoint coverage)
  int myu = 0;
  for (int i = t; i < n; i += 256) {
    const unsigned int u = u_lds[i];
    const int idx = (int)i_lds[i];
    const bool kp = (u > tu) || (u == tu && idx <= ti_);
    out[idx] = kp ? (float)e : -1.0f;
    out[NSLOT + idx] = kp ? __uint_as_float(u) : 0.0f;
    myu += (kp && ((idx & 1) == 0)) ? 1 : 0;
  }
#pragma unroll
  for (int off = 32; off > 0; off >>= 1) myu += __shfl_xor(myu, off, 64);
  __syncthreads();  // wtot reuse
  if (lane == 0) wtot[wid] = myu;
  __syncthreads();
  if (t == 0) usage[e] = wtot[0] + wtot[1] + wtot[2] + wtot[3];
}

// ------------------------------------------------- losses
__global__ __launch_bounds__(256) void k_loss(const float* __restrict__ partials,
                                              const int* __restrict__ usage,
                                              float* __restrict__ out) {
  const int t = threadIdx.x, lane = t & 63, wid = t >> 6;
  float a[9];
#pragma unroll
  for (int m = 0; m < 9; ++m) a[m] = 0.f;
  for (int r = t; r < 1024; r += 256)
#pragma unroll
    for (int m = 0; m < 9; ++m) a[m] += partials[r * 9 + m];
  __shared__ float wred[4][9];
#pragma unroll
  for (int m = 0; m < 9; ++m) {
    float v = a[m];
#pragma unroll
    for (int off = 32; off > 0; off >>= 1) v += __shfl_xor(v, off, 64);
    if (lane == 0) wred[wid][m] = v;
  }
  __syncthreads();
  if (t == 0) {
    float ps[9];
#pragma unroll
    for (int m = 0; m < 9; ++m)
      ps[m] = wred[0][m] + wred[1][m] + wred[2][m] + wred[3][m];
    float lb = 0.f;
    for (int e = 0; e < 8; ++e) lb += ps[e] * (float)usage[e];
    out[2 * NSLOT]     = lb * (0.01f / (float)(NT * NE));
    out[2 * NSLOT + 1] = (ps[8] / (float)NT) * 0.001f;
  }
  if (t >= 8 && t < 16) out[2 * NSLOT + 2 + (t - 8)] = (float)usage[t - 8];
}

extern "C" void kernel_launch(void* const* d_in, const int* in_sizes, int n_in,
                              void* d_out, int out_size, void* d_ws, size_t ws_size,
                              hipStream_t stream) {
  const float* x  = (const float*)d_in[0];
  const float* gw = (const float*)d_in[1];
  float* out = (float*)d_out;
  char* ws = (char*)d_ws;

  float* topk_p         = (float*)(ws);                    // 65536 B
  unsigned char* flat_e = (unsigned char*)(ws + 65536);    // 16384 B
  float* partials       = (float*)(ws + 81920);            // 36864 B
  int* usage            = (int*)(ws + 118784);             // 32 B

  hipLaunchKernelGGL(k_logits_route, dim3(1024), dim3(256), 0, stream, x, gw,
                     topk_p, flat_e, partials);
  hipLaunchKernelGGL(k_select_final, dim3(8), dim3(256), 0, stream, topk_p,
                     flat_e, out, usage);
  hipLaunchKernelGGL(k_loss, dim3(1), dim3(256), 0, stream, partials, usage, out);
}

// Round 8
// 53.239 us; speedup vs baseline: 1.6726x; 1.0425x over previous
//
#include <hip/hip_runtime.h>

#define NT 8192
#define DM 4096
#define NE 8
#define NSLOT 16384
#define CAP 1024

// ------------------------------------------------- fused logits + routing
// 1024 blocks x 256 threads; wave = 2 tokens x full 4096-dim row.
// After the cross-lane reduce, lanes 0/1 compute softmax/top-2/losses for
// their token inline. Outputs: topk_p, flat_e, per-block partials[9].
// Also zeroes the cross-block completion counter used by k_select_final.
__global__ __launch_bounds__(256, 4) void k_logits_route(
    const float* __restrict__ x, const float* __restrict__ gw,
    float* __restrict__ topk_p, unsigned char* __restrict__ flat_e,
    float* __restrict__ partials, int* __restrict__ counter) {
  const int tid = threadIdx.x;
  const int lane = tid & 63;
  const int wv = tid >> 6;                 // 0..3
  const int wave = blockIdx.x * 4 + wv;    // 0..4095
  const int t0 = wave * 2;
  const float4* __restrict__ xv = (const float4*)x;
  const float4* __restrict__ gv = (const float4*)gw;

  if (blockIdx.x == 0 && tid == 0) *counter = 0;  // stream-ordered vs K2

  float acc[2][8];
#pragma unroll
  for (int t = 0; t < 2; ++t)
#pragma unroll
    for (int e = 0; e < 8; ++e) acc[t][e] = 0.f;

#pragma unroll 2
  for (int c = 0; c < 16; ++c) {
    const int off = c * 64 + lane;
    float4 g4[8];
#pragma unroll
    for (int e = 0; e < 8; ++e) g4[e] = gv[e * 1024 + off];
    const float4 x0 = xv[(size_t)t0 * 1024 + off];
    const float4 x1 = xv[(size_t)t0 * 1024 + 1024 + off];
#pragma unroll
    for (int e = 0; e < 8; ++e) {
      acc[0][e] = fmaf(x0.x, g4[e].x, acc[0][e]);
      acc[0][e] = fmaf(x0.y, g4[e].y, acc[0][e]);
      acc[0][e] = fmaf(x0.z, g4[e].z, acc[0][e]);
      acc[0][e] = fmaf(x0.w, g4[e].w, acc[0][e]);
      acc[1][e] = fmaf(x1.x, g4[e].x, acc[1][e]);
      acc[1][e] = fmaf(x1.y, g4[e].y, acc[1][e]);
      acc[1][e] = fmaf(x1.z, g4[e].z, acc[1][e]);
      acc[1][e] = fmaf(x1.w, g4[e].w, acc[1][e]);
    }
  }

  // cross-lane reduce: lane t*8+e ends up holding logit[t][e]
  float val = 0.f;
#pragma unroll
  for (int t = 0; t < 2; ++t)
#pragma unroll
    for (int e = 0; e < 8; ++e) {
      float v = acc[t][e];
#pragma unroll
      for (int s = 32; s > 0; s >>= 1) v += __shfl_xor(v, s, 64);
      if (lane == t * 8 + e) val = v;
    }

  // gather the 8 logits of token (lane&1) into every lane
  float l[8];
#pragma unroll
  for (int e = 0; e < 8; ++e) l[e] = __shfl(val, (lane & 1) * 8 + e, 64);

  // routing math (meaningful on lanes 0/1; harmless elsewhere)
  float m = l[0];
#pragma unroll
  for (int e = 1; e < 8; ++e) m = fmaxf(m, l[e]);
  float ex[8];
  float s = 0.f;
#pragma unroll
  for (int e = 0; e < 8; ++e) { ex[e] = expf(l[e] - m); s += ex[e]; }
  const float lse = m + logf(s);

  float b0 = l[0]; int i0 = 0;
#pragma unroll
  for (int e = 1; e < 8; ++e) if (l[e] > b0) { b0 = l[e]; i0 = e; }
  float b1 = -3.4e38f; int i1 = 0;
#pragma unroll
  for (int e = 0; e < 8; ++e) if (e != i0 && l[e] > b1) { b1 = l[e]; i1 = e; }

  const float t1 = expf(b1 - b0);
  const float ss = 1.f + t1;
  float p0 = 1.f / ss, p1 = t1 / ss;
  float s2 = p0 + p1;
  s2 = fmaxf(s2, 1e-8f);
  p0 /= s2; p1 /= s2;

  __shared__ float pr[8][9];
  if (lane < 2) {
    const int tok = t0 + lane;
    topk_p[2 * tok] = p0; topk_p[2 * tok + 1] = p1;
    flat_e[2 * tok] = (unsigned char)i0; flat_e[2 * tok + 1] = (unsigned char)i1;
#pragma unroll
    for (int e = 0; e < 8; ++e) pr[wv * 2 + lane][e] = ex[e] / s;
    pr[wv * 2 + lane][8] = lse * lse;
  }
  __syncthreads();
  if (tid < 9) {
    float a = 0.f;
#pragma unroll
    for (int r = 0; r < 8; ++r) a += pr[r][tid];
    partials[blockIdx.x * 9 + tid] = a;
  }
}

// ------------------------------------------- fused select + finalize + loss
// One block per expert. Compact this expert's (u, idx) pairs into LDS, run
// exact radix threshold if over capacity, write this expert's output slots
// (disjoint coverage, no atomics), its usage, and its lb-loss product.
// The last block to finish (device atomic counter) sums the 8 products in
// fixed order e=0..7 and writes lb/z losses — fully deterministic.
__global__ __launch_bounds__(256) void k_select_final(
    const float* __restrict__ flat_p, const unsigned char* __restrict__ flat_e,
    const float* __restrict__ partials, float* __restrict__ out,
    float* __restrict__ prod, float* __restrict__ zsum,
    int* __restrict__ counter) {
  const int e = blockIdx.x;
  const int t = threadIdx.x;
  const int lane = t & 63, wid = t >> 6;
  __shared__ unsigned int u_lds[NSLOT];     // 64 KB
  __shared__ unsigned short i_lds[NSLOT];   // 32 KB
  __shared__ int hist[4][1024];             // 16 KB
  __shared__ int wtot[4];
  __shared__ float fA[4], fZ[4];
  __shared__ int s_n, s_b, s_R2, s_cn, s_ti;
  __shared__ int s_cand[16];

  const uint4* __restrict__ e4p = (const uint4*)flat_e;
  const float4* __restrict__ p4p = (const float4*)flat_p;

  // ---- phase 1: count my matches
  int mycnt = 0;
#pragma unroll
  for (int it = 0; it < 4; ++it) {
    const uint4 ev = e4p[t + it * 256];
    const unsigned int w[4] = {ev.x, ev.y, ev.z, ev.w};
#pragma unroll
    for (int q = 0; q < 4; ++q)
#pragma unroll
      for (int b = 0; b < 4; ++b)
        mycnt += (((w[q] >> (8 * b)) & 0xffu) == (unsigned)e);
  }
  int pfx = mycnt;
#pragma unroll
  for (int off = 1; off < 64; off <<= 1) {
    const int tmp = __shfl_up(pfx, off, 64);
    if (lane >= off) pfx += tmp;
  }
  if (lane == 63) wtot[wid] = pfx;
  __syncthreads();
  int wbefore = 0;
  for (int w = 0; w < wid; ++w) wbefore += wtot[w];
  int pos = wbefore + pfx - mycnt;
  if (t == 255) s_n = wbefore + pfx;
  __syncthreads();
  const int n = s_n;

  // ---- phase 2: compact (always)
#pragma unroll
  for (int it = 0; it < 4; ++it) {
    const int vidx = t + it * 256;
    const uint4 ev = e4p[vidx];
    const unsigned int w[4] = {ev.x, ev.y, ev.z, ev.w};
    float4 pv[4];
#pragma unroll
    for (int q = 0; q < 4; ++q) pv[q] = p4p[vidx * 4 + q];
#pragma unroll
    for (int q = 0; q < 4; ++q) {
      const float pf[4] = {pv[q].x, pv[q].y, pv[q].z, pv[q].w};
#pragma unroll
      for (int b = 0; b < 4; ++b) {
        if (((w[q] >> (8 * b)) & 0xffu) == (unsigned)e) {
          u_lds[pos] = __float_as_uint(pf[b]);
          i_lds[pos] = (unsigned short)(vidx * 16 + q * 4 + b);
          ++pos;
        }
      }
    }
  }
  __syncthreads();

  unsigned int tu = 0u;
  int ti_ = 0x7FFFFFFF;
  if (n > CAP) {
    // ---- radix on u (descending), 10 bits/pass, bits 29..0
    int R = CAP;
    unsigned int pref = 0;
    for (int pass = 0; pass < 3; ++pass) {
      const int shift = 20 - 10 * pass;
      for (int i = t; i < 4096; i += 256) ((int*)hist)[i] = 0;
      __syncthreads();
      for (int i = t; i < n; i += 256) {
        const unsigned int u = u_lds[i];
        if ((u >> (shift + 10)) == pref)
          atomicAdd(&hist[wid][(u >> shift) & 1023], 1);
      }
      __syncthreads();
      int c[4], chunk = 0;
#pragma unroll
      for (int k = 0; k < 4; ++k) {
        c[k] = hist[0][4 * t + k] + hist[1][4 * t + k] + hist[2][4 * t + k] +
               hist[3][4 * t + k];
        chunk += c[k];
      }
      int sfx = chunk;
#pragma unroll
      for (int off = 1; off < 64; off <<= 1) {
        const int tmp = __shfl_down(sfx, off, 64);
        if (lane + off < 64) sfx += tmp;
      }
      if (lane == 0) wtot[wid] = sfx;
      __syncthreads();
      int wafter = 0;
      for (int w = wid + 1; w < 4; ++w) wafter += wtot[w];
      const int after = sfx + wafter - chunk;
      if (after < R && after + chunk >= R) {
        int sx = after, bf = -1, rf = 0;
#pragma unroll
        for (int k = 3; k >= 0; --k) {
          if (bf < 0 && sx < R && sx + c[k] >= R) { bf = 4 * t + k; rf = R - sx; }
          sx += c[k];
        }
        s_b = bf; s_R2 = rf;
      }
      __syncthreads();
      pref = (pref << 10) | (unsigned int)s_b;
      R = s_R2;
      __syncthreads();
    }
    const unsigned int ustar = pref;

    // ---- ascending idx pass among u == ustar
    for (int i = t; i < 4096; i += 256) ((int*)hist)[i] = 0;
    if (t == 0) s_cn = 0;
    __syncthreads();
    for (int i = t; i < n; i += 256) {
      if (u_lds[i] == ustar) atomicAdd(&hist[wid][i_lds[i] >> 4], 1);
    }
    __syncthreads();
    int c[4], chunk = 0;
#pragma unroll
    for (int k = 0; k < 4; ++k) {
      c[k] = hist[0][4 * t + k] + hist[1][4 * t + k] + hist[2][4 * t + k] +
             hist[3][4 * t + k];
      chunk += c[k];
    }
    int pfa = chunk;
#pragma unroll
    for (int off = 1; off < 64; off <<= 1) {
      const int tmp = __shfl_up(pfa, off, 64);
      if (lane >= off) pfa += tmp;
    }
    if (lane == 63) wtot[wid] = pfa;
    __syncthreads();
    int wb = 0;
    for (int w = 0; w < wid; ++w) wb += wtot[w];
    const int before = wb + pfa - chunk;
    if (before < R && before + chunk >= R) {
      int cum = before, bf = -1, rf = 0;
#pragma unroll
      for (int k = 0; k < 4; ++k) {
        if (bf < 0 && cum < R && cum + c[k] >= R) { bf = 4 * t + k; rf = R - cum; }
        cum += c[k];
      }
      s_b = bf; s_R2 = rf;
    }
    __syncthreads();
    const int b3 = s_b, R4 = s_R2;
    for (int i = t; i < n; i += 256) {
      if (u_lds[i] == ustar && (i_lds[i] >> 4) == b3)
        s_cand[atomicAdd(&s_cn, 1)] = (int)i_lds[i];
    }
    __syncthreads();
    if (t == 0) {
      const int cn = s_cn;
      int ans = 0x7FFFFFFF;
      for (int a = 0; a < cn; ++a) {
        int r = 0;
        for (int b = 0; b < cn; ++b) r += (s_cand[b] < s_cand[a]);
        if (r == R4 - 1) ans = s_cand[a];
      }
      s_ti = ans;
    }
    __syncthreads();
    tu = ustar;
    ti_ = s_ti;
  }

  // ---- output phase: exactly this expert's slots (disjoint coverage)
  int myu = 0;
  for (int i = t; i < n; i += 256) {
    const unsigned int u = u_lds[i];
    const int idx = (int)i_lds[i];
    const bool kp = (u > tu) || (u == tu && idx <= ti_);
    out[idx] = kp ? (float)e : -1.0f;
    out[NSLOT + idx] = kp ? __uint_as_float(u) : 0.0f;
    myu += (kp && ((idx & 1) == 0)) ? 1 : 0;
  }
#pragma unroll
  for (int off = 32; off > 0; off >>= 1) myu += __shfl_xor(myu, off, 64);

  // ---- loss phase: ps[e] (+ z partial on block 0) over 1024 block-partials
  float a = 0.f, z = 0.f;
  for (int r = t; r < 1024; r += 256) {
    a += partials[r * 9 + e];
    if (e == 0) z += partials[r * 9 + 8];
  }
#pragma unroll
  for (int off = 32; off > 0; off >>= 1) {
    a += __shfl_xor(a, off, 64);
    z += __shfl_xor(z, off, 64);
  }
  __syncthreads();  // before reusing wtot / writing fA,fZ
  if (lane == 0) { wtot[wid] = myu; fA[wid] = a; fZ[wid] = z; }
  __syncthreads();
  if (t == 0) {
    const int use = wtot[0] + wtot[1] + wtot[2] + wtot[3];
    const float ps_e = fA[0] + fA[1] + fA[2] + fA[3];
    out[2 * NSLOT + 2 + e] = (float)use;
    prod[e] = ps_e * (float)use;
    if (e == 0) *zsum = fZ[0] + fZ[1] + fZ[2] + fZ[3];
    __threadfence();
    const int old = atomicAdd(counter, 1);
    if (old == NE - 1) {  // last block: deterministic fixed-order sum
      __threadfence();
      float lb = 0.f;
#pragma unroll
      for (int q = 0; q < 8; ++q) lb += prod[q];
      out[2 * NSLOT]     = lb * (0.01f / (float)(NT * NE));
      out[2 * NSLOT + 1] = (*zsum / (float)NT) * 0.001f;
    }
  }
}

extern "C" void kernel_launch(void* const* d_in, const int* in_sizes, int n_in,
                              void* d_out, int out_size, void* d_ws, size_t ws_size,
                              hipStream_t stream) {
  const float* x  = (const float*)d_in[0];
  const float* gw = (const float*)d_in[1];
  float* out = (float*)d_out;
  char* ws = (char*)d_ws;

  float* topk_p         = (float*)(ws);                    // 65536 B
  unsigned char* flat_e = (unsigned char*)(ws + 65536);    // 16384 B
  float* partials       = (float*)(ws + 81920);            // 36864 B
  float* prod           = (float*)(ws + 118784);           // 32 B
  float* zsum           = (float*)(ws + 118816);           // 4 B
  int* counter          = (int*)(ws + 118848);             // 4 B

  hipLaunchKernelGGL(k_logits_route, dim3(1024), dim3(256), 0, stream, x, gw,
                     topk_p, flat_e, partials, counter);
  hipLaunchKernelGGL(k_select_final, dim3(8), dim3(256), 0, stream, topk_p,
                     flat_e, partials, out, prod, zsum, counter);
}